// Round 1
// baseline (465.742 us; speedup 1.0000x reference)
//
#include <hip/hip_runtime.h>
#include <math.h>

#define BT 128   // block size: 2 waves of 64

// ---------- activation helpers (fp32, exact-erf GELU) ----------
__device__ __forceinline__ float gelu_erf(float v){
  // gelu(x) = 0.5 x (1 + erf(x/sqrt(2))), erf via Abramowitz-Stegun 7.1.26 (|eps|<=1.5e-7)
  float z  = v * 0.70710678118654752f;
  float az = fabsf(z);
  float t  = 1.0f / (1.0f + 0.3275911f * az);
  float poly = t*(0.254829592f + t*(-0.284496736f + t*(1.421413741f + t*(-1.453152027f + t*1.061405429f))));
  float ex = __expf(-az*az);
  float erfv = 1.0f - poly*ex;
  erfv = (z < 0.0f) ? -erfv : erfv;
  return 0.5f * v * (1.0f + erfv);
}

__device__ __forceinline__ float tanh_fast(float v){
  // tanh(x) = 1 - 2/(e^{2x}+1); stable at both ends (inf -> 1, 0 -> -1)
  float t = __expf(2.0f*v);
  return 1.0f - 2.0f/(t + 1.0f);
}

// ---------- prep kernel: fold weights (runs once per launch, 1 block) ----------
// ws layout (floats): A[1024] | wvec[32] | M[1024] | bM[32]   (total 2112 floats)
//   A[d][k]  = sum_m Wq[m,d] * Wk[m,k]           (WqT Wk)
//   wvec[k]  = sum_m bq[m] * Wk[m,k]             (WkT bq)
//   M[j][d]  = (W_ih * OP * WV)[j][d]
//   bM[j]    = (W_ih * (OP bv + opb))[j] + b_ih[j] + b_hh[j]
__global__ void prep_kernel(const float* __restrict__ inw, const float* __restrict__ inb,
                            const float* __restrict__ opw, const float* __restrict__ opb,
                            const float* __restrict__ wih, const float* __restrict__ bih,
                            const float* __restrict__ bhh, float* __restrict__ ws){
  __shared__ float sOPWV[1024];
  __shared__ float sT[32];
  int tx = threadIdx.x & 31;
  int ty = threadIdx.x >> 5;
  float accA = 0.f, accP = 0.f;
  #pragma unroll
  for (int m = 0; m < 32; m++){
    accA += inw[m*32 + ty] * inw[1024 + m*32 + tx];   // Wq[m,ty] * Wk[m,tx]
    accP += opw[ty*32 + m] * inw[2048 + m*32 + tx];   // OP[ty,m] * WV[m,tx]
  }
  ws[ty*32 + tx] = accA;
  sOPWV[ty*32 + tx] = accP;
  if (ty == 0){
    float aw = 0.f;
    #pragma unroll
    for (int m = 0; m < 32; m++) aw += inb[m] * inw[1024 + m*32 + tx];  // bq[m]*Wk[m,tx]
    ws[1024 + tx] = aw;
  }
  if (ty == 1){
    float at = opb[tx];
    #pragma unroll
    for (int m = 0; m < 32; m++) at += opw[tx*32 + m] * inb[64 + m];    // OP[tx,m]*bv[m]
    sT[tx] = at;
  }
  __syncthreads();
  float accM = 0.f;
  #pragma unroll
  for (int m = 0; m < 32; m++) accM += wih[ty*32 + m] * sOPWV[m*32 + tx];
  ws[1056 + ty*32 + tx] = accM;
  if (ty == 2){
    float ab = bih[tx] + bhh[tx];
    #pragma unroll
    for (int m = 0; m < 32; m++) ab += wih[tx*32 + m] * sT[m];
    ws[2080 + tx] = ab;
  }
}

// ---------- main fused kernel: one thread per batch element ----------
__global__ __launch_bounds__(BT) void fused_kernel(
    const float* __restrict__ x,
    const float* __restrict__ embw, const float* __restrict__ embb,
    const float* __restrict__ ws,
    const float* __restrict__ whh,
    const float* __restrict__ decw, const float* __restrict__ decb,
    const float* __restrict__ outw, const float* __restrict__ outb,
    float* __restrict__ y, int B)
{
  // per-WAVE slab (64 lanes x 64 floats); lanes are lockstep, so e-phase strictly
  // precedes h-phase within a wave -> aliasing hbuf over ebuf is race-free, no barriers.
  __shared__ float smem[(BT/64) * 64 * 64];
  const float* A    = ws;
  const float* wvec = ws + 1024;
  const float* M    = ws + 1056;
  const float* bM   = ws + 2080;

  int tid  = threadIdx.x;
  int lane = tid & 63;
  float*  slab = smem + (tid >> 6) * (64*64);
  float2* ebuf = (float2*)slab;   // ebuf[k*64 + lane] = (e0[k], e1[k]) column layout (conflict-free)
  float*  hbuf = slab;            // aliases; used after e is dead

  long long b = (long long)blockIdx.x * BT + tid;
  if (b >= B) return;

  // ---- load x[b]: 10 floats (8B aligned -> float2)
  const float2* xp = (const float2*)(x + b*10ll);
  float2 p0 = xp[0], p1 = xp[1], p2 = xp[2], p3 = xp[3], p4 = xp[4];
  float x0[5] = {p0.x, p0.y, p1.x, p1.y, p2.x};
  float x1[5] = {p2.y, p3.x, p3.y, p4.x, p4.y};

  // ---- embedding + gelu -> LDS (rolled loop; weights are uniform s_loads)
  #pragma unroll 1
  for (int j = 0; j < 32; j++){
    const float* wr = embw + j*5;
    float w0 = wr[0], w1 = wr[1], w2 = wr[2], w3 = wr[3], w4 = wr[4];
    float bb = embb[j];
    float a0 = bb + x0[0]*w0 + x0[1]*w1 + x0[2]*w2 + x0[3]*w3 + x0[4]*w4;
    float a1 = bb + x1[0]*w0 + x1[1]*w1 + x1[2]*w2 + x1[3]*w3 + x1[4]*w4;
    ebuf[j*64 + lane] = make_float2(gelu_erf(a0), gelu_erf(a1));
  }

  // ---- restore e to registers (constant-indexed ds_reads)
  float e0[32], e1[32];
  #pragma unroll
  for (int k = 0; k < 32; k++){
    float2 v = ebuf[k*64 + lane];
    e0[k] = v.x; e1[k] = v.y;
  }

  // ---- score pass: s_ij = e_i^T A e_j ; dw = wvec . (e1 - e0)
  float s00=0.f, s01=0.f, s10=0.f, s11=0.f, dw=0.f;
  #pragma unroll 1
  for (int d = 0; d < 32; d++){
    const float* Ar = A + d*32;
    float g0a=0.f, g0b=0.f, g1a=0.f, g1b=0.f;
    #pragma unroll
    for (int k = 0; k < 32; k += 2){
      float aa = Ar[k], ab = Ar[k+1];
      g0a += aa*e0[k];   g0b += ab*e0[k+1];
      g1a += aa*e1[k];   g1b += ab*e1[k+1];
    }
    float g0 = g0a + g0b, g1 = g1a + g1b;
    float2 ed = ebuf[d*64 + lane];          // runtime-indexed e via LDS
    s00 += ed.x*g0;  s01 += ed.x*g1;
    s10 += ed.y*g0;  s11 += ed.y*g1;
    dw  += wvec[d]*(ed.y - ed.x);
  }

  // ---- 2-way softmax: shared terms (u.e_i + c) cancel in the row-wise softmax
  const float iss = 0.17677669529663689f;   // 1/sqrt(32)
  float a01 = 1.0f/(1.0f + __expf(-((s01 - s00 + dw)*iss)));
  float a11 = 1.0f/(1.0f + __expf(-((s11 - s10 + dw)*iss)));
  float a00 = 1.0f - a01, a10 = 1.0f - a11;

  // ---- c_i = a_i0 e0 + a_i1 e1 (in place; rows of attn sum to 1 -> bv folds into bM)
  #pragma unroll
  for (int k = 0; k < 32; k++){
    float t0 = e0[k], t1 = e1[k];
    e0[k] = a00*t0 + a01*t1;   // c0
    e1[k] = a10*t0 + a11*t1;   // c1
  }

  // ---- h1 = tanh(M c0 + bM) -> LDS
  #pragma unroll 1
  for (int j = 0; j < 32; j++){
    const float* Mr = M + j*32;
    float q0=0.f,q1=0.f,q2=0.f,q3=0.f;
    #pragma unroll
    for (int k = 0; k < 32; k += 4){
      q0 += Mr[k]*e0[k];     q1 += Mr[k+1]*e0[k+1];
      q2 += Mr[k+2]*e0[k+2]; q3 += Mr[k+3]*e0[k+3];
    }
    hbuf[j*64 + lane] = tanh_fast(bM[j] + (q0+q1) + (q2+q3));
  }
  float h1[32];
  #pragma unroll
  for (int k = 0; k < 32; k++) h1[k] = hbuf[k*64 + lane];

  // ---- h2 = tanh(M c1 + bM + Whh h1) -> LDS
  #pragma unroll 1
  for (int j = 0; j < 32; j++){
    const float* Mr = M + j*32;
    const float* Wr = whh + j*32;
    float q0=0.f,q1=0.f,q2=0.f,q3=0.f;
    #pragma unroll
    for (int k = 0; k < 32; k += 2){
      q0 += Mr[k]*e1[k];   q1 += Mr[k+1]*e1[k+1];
      q2 += Wr[k]*h1[k];   q3 += Wr[k+1]*h1[k+1];
    }
    hbuf[j*64 + lane] = tanh_fast(bM[j] + (q0+q1) + (q2+q3));
  }
  float h2[32];
  #pragma unroll
  for (int k = 0; k < 32; k++) h2[k] = hbuf[k*64 + lane];

  // ---- decode (gelu) + final linear
  float dv[5];
  #pragma unroll
  for (int i = 0; i < 5; i++){
    const float* dr = decw + i*32;
    float q0=0.f,q1=0.f,q2=0.f,q3=0.f;
    #pragma unroll
    for (int k = 0; k < 32; k += 4){
      q0 += dr[k]*h2[k];     q1 += dr[k+1]*h2[k+1];
      q2 += dr[k+2]*h2[k+2]; q3 += dr[k+3]*h2[k+3];
    }
    dv[i] = gelu_erf(decb[i] + (q0+q1) + (q2+q3));
  }
  float* yp = y + b*3ll;
  #pragma unroll
  for (int r = 0; r < 3; r++){
    yp[r] = outb[r] + outw[r*5+0]*dv[0] + outw[r*5+1]*dv[1]
                    + outw[r*5+2]*dv[2] + outw[r*5+3]*dv[3] + outw[r*5+4]*dv[4];
  }
}

extern "C" void kernel_launch(void* const* d_in, const int* in_sizes, int n_in,
                              void* d_out, int out_size, void* d_ws, size_t ws_size,
                              hipStream_t stream){
  const float* x    = (const float*)d_in[0];
  const float* embw = (const float*)d_in[1];
  const float* embb = (const float*)d_in[2];
  const float* inw  = (const float*)d_in[3];
  const float* inb  = (const float*)d_in[4];
  const float* opw  = (const float*)d_in[5];
  const float* opb  = (const float*)d_in[6];
  const float* wih  = (const float*)d_in[7];
  const float* bih  = (const float*)d_in[8];
  const float* whh  = (const float*)d_in[9];
  const float* bhh  = (const float*)d_in[10];
  const float* decw = (const float*)d_in[11];
  const float* decb = (const float*)d_in[12];
  const float* outw = (const float*)d_in[13];
  const float* outb = (const float*)d_in[14];
  float* y  = (float*)d_out;
  float* ws = (float*)d_ws;   // needs 2112 floats (8.4 KB)

  int B = in_sizes[0] / 10;   // [B,2,5]

  prep_kernel<<<1, 1024, 0, stream>>>(inw, inb, opw, opb, wih, bih, bhh, ws);
  fused_kernel<<<(B + BT - 1)/BT, BT, 0, stream>>>(x, embw, embb, ws, whh,
                                                   decw, decb, outw, outb, y, B);
}

// Round 2
// 325.454 us; speedup vs baseline: 1.4311x; 1.4311x over previous
//
#include <hip/hip_runtime.h>
#include <math.h>

#define BT 128   // block size: 2 waves of 64

// ---------- activation helpers (fp32, exact-erf GELU) ----------
__device__ __forceinline__ float gelu_erf(float v){
  // gelu(x) = 0.5 x (1 + erf(x/sqrt(2))), erf via Abramowitz-Stegun 7.1.26 (|eps|<=1.5e-7)
  float z  = v * 0.70710678118654752f;
  float az = fabsf(z);
  float t  = 1.0f / (1.0f + 0.3275911f * az);
  float poly = t*(0.254829592f + t*(-0.284496736f + t*(1.421413741f + t*(-1.453152027f + t*1.061405429f))));
  float ex = __expf(-az*az);
  float erfv = 1.0f - poly*ex;
  erfv = (z < 0.0f) ? -erfv : erfv;
  return 0.5f * v * (1.0f + erfv);
}

__device__ __forceinline__ float tanh_fast(float v){
  // tanh(x) = 1 - 2/(e^{2x}+1); stable at both ends
  float t = __expf(2.0f*v);
  return 1.0f - 2.0f/(t + 1.0f);
}

// pack (lo=f2bf(a), hi=f2bf(b)) with RNE rounding; unpack is 1 VALU op each
__device__ __forceinline__ unsigned int pack_bf(float a, float b){
  unsigned int ua = __float_as_uint(a);
  unsigned int ub = __float_as_uint(b);
  ua = (ua + 0x7fffu + ((ua >> 16) & 1u)) >> 16;
  ub = (ub + 0x7fffu + ((ub >> 16) & 1u)) & 0xffff0000u;
  return ub | ua;
}

// ---------- prep kernel: fold weights (runs once per launch, 1 block) ----------
// ws layout (floats): A[1024] | wvec[32] | M[1024] | bM[32]
//   A[d][k]  = sum_m Wq[m,d] * Wk[m,k]           (WqT Wk)
//   wvec[k]  = sum_m bq[m] * Wk[m,k]             (WkT bq)
//   M[j][d]  = (W_ih * OP * WV)[j][d]
//   bM[j]    = (W_ih * (OP bv + opb))[j] + b_ih[j] + b_hh[j]
__global__ void prep_kernel(const float* __restrict__ inw, const float* __restrict__ inb,
                            const float* __restrict__ opw, const float* __restrict__ opb,
                            const float* __restrict__ wih, const float* __restrict__ bih,
                            const float* __restrict__ bhh, float* __restrict__ ws){
  __shared__ float sOPWV[1024];
  __shared__ float sT[32];
  int tx = threadIdx.x & 31;
  int ty = threadIdx.x >> 5;
  float accA = 0.f, accP = 0.f;
  #pragma unroll
  for (int m = 0; m < 32; m++){
    accA += inw[m*32 + ty] * inw[1024 + m*32 + tx];   // Wq[m,ty] * Wk[m,tx]
    accP += opw[ty*32 + m] * inw[2048 + m*32 + tx];   // OP[ty,m] * WV[m,tx]
  }
  ws[ty*32 + tx] = accA;
  sOPWV[ty*32 + tx] = accP;
  if (ty == 0){
    float aw = 0.f;
    #pragma unroll
    for (int m = 0; m < 32; m++) aw += inb[m] * inw[1024 + m*32 + tx];  // bq[m]*Wk[m,tx]
    ws[1024 + tx] = aw;
  }
  if (ty == 1){
    float at = opb[tx];
    #pragma unroll
    for (int m = 0; m < 32; m++) at += opw[tx*32 + m] * inb[64 + m];    // OP[tx,m]*bv[m]
    sT[tx] = at;
  }
  __syncthreads();
  float accM = 0.f;
  #pragma unroll
  for (int m = 0; m < 32; m++) accM += wih[ty*32 + m] * sOPWV[m*32 + tx];
  ws[1056 + ty*32 + tx] = accM;
  if (ty == 2){
    float ab = bih[tx] + bhh[tx];
    #pragma unroll
    for (int m = 0; m < 32; m++) ab += wih[tx*32 + m] * sT[m];
    ws[2080 + tx] = ab;
  }
}

// ---------- main fused kernel: one thread per batch element ----------
__global__ __launch_bounds__(BT) void fused_kernel(
    const float* __restrict__ x,
    const float* __restrict__ embw, const float* __restrict__ embb,
    const float* __restrict__ ws,
    const float* __restrict__ whh,
    const float* __restrict__ decw, const float* __restrict__ decb,
    const float* __restrict__ outw, const float* __restrict__ outb,
    float* __restrict__ y, int B)
{
  // per-WAVE slab: 32 rows x 64 lanes x 4 B = 8 KB/wave -> 16 KB/block.
  // Phase 1: packed bf16 (e0, delta). Phase 2 (after score pass): fp32 h1 (aliased).
  // Wave lockstep makes the alias race-free; [row][lane] layout is conflict-free.
  __shared__ unsigned int smem[(BT/64) * 32 * 64];
  const float* A    = ws;
  const float* wvec = ws + 1024;
  const float* M    = ws + 1056;
  const float* bM   = ws + 2080;

  int tid  = threadIdx.x;
  int lane = tid & 63;
  unsigned int* eslab = smem + (tid >> 6) * (32*64);
  float*        hbuf  = (float*)eslab;

  long long b = (long long)blockIdx.x * BT + tid;
  if (b >= B) return;

  // ---- load x[b]: 10 floats (8B aligned -> float2)
  const float2* xp = (const float2*)(x + b*10ll);
  float2 p0 = xp[0], p1 = xp[1], p2 = xp[2], p3 = xp[3], p4 = xp[4];
  float x0[5] = {p0.x, p0.y, p1.x, p1.y, p2.x};
  float x1[5] = {p2.y, p3.x, p3.y, p4.x, p4.y};

  // ---- embedding + gelu -> LDS as packed bf16 (e0, delta = e1 - e0)
  #pragma unroll 1
  for (int j = 0; j < 32; j++){
    const float* wr = embw + j*5;
    float w0 = wr[0], w1 = wr[1], w2 = wr[2], w3 = wr[3], w4 = wr[4];
    float bb = embb[j];
    float a0 = bb + x0[0]*w0 + x0[1]*w1 + x0[2]*w2 + x0[3]*w3 + x0[4]*w4;
    float a1 = bb + x1[0]*w0 + x1[1]*w1 + x1[2]*w2 + x1[3]*w3 + x1[4]*w4;
    float g0 = gelu_erf(a0);
    float g1 = gelu_erf(a1);
    eslab[j*64 + lane] = pack_bf(g0, g1 - g0);
  }

  // ---- restore (e0, delta) to registers (constant-indexed ds_reads)
  float e0[32], dl[32];
  #pragma unroll
  for (int k = 0; k < 32; k++){
    unsigned int u = eslab[k*64 + lane];
    e0[k] = __uint_as_float(u << 16);
    dl[k] = __uint_as_float(u & 0xffff0000u);
  }

  // ---- score pass (delta identity): g = A*delta; t0 = e0.g, t1 = delta.g, dw = wvec.delta
  float t0 = 0.f, t1 = 0.f, dw = 0.f;
  #pragma unroll 1
  for (int d = 0; d < 32; d++){
    const float* Ar = A + d*32;
    float q0=0.f,q1=0.f,q2=0.f,q3=0.f;
    #pragma unroll
    for (int k = 0; k < 32; k += 4){
      q0 += Ar[k]*dl[k];     q1 += Ar[k+1]*dl[k+1];
      q2 += Ar[k+2]*dl[k+2]; q3 += Ar[k+3]*dl[k+3];
    }
    float g = (q0+q1) + (q2+q3);
    unsigned int u = eslab[d*64 + lane];           // runtime-indexed e via LDS
    float e0d = __uint_as_float(u << 16);
    float dld = __uint_as_float(u & 0xffff0000u);
    t0 += e0d*g;  t1 += dld*g;  dw += wvec[d]*dld;
  }

  // ---- 2-way softmax on logit differences (shared terms cancel)
  const float iss = 0.17677669529663689f;   // 1/sqrt(32)
  float a01 = 1.0f/(1.0f + __expf(-((t0      + dw)*iss)));
  float a11 = 1.0f/(1.0f + __expf(-((t0 + t1 + dw)*iss)));

  // ---- c_i = e0 + a_i1 * delta  (rows of attn sum to 1; bv folded into bM)
  #pragma unroll
  for (int k = 0; k < 32; k++){
    float b0 = e0[k], dd = dl[k];
    e0[k] = b0 + a01*dd;   // c0
    dl[k] = b0 + a11*dd;   // c1
  }

  // ---- h1 = tanh(M c0 + bM) -> LDS (fp32, aliases dead e-slab)
  #pragma unroll 1
  for (int j = 0; j < 32; j++){
    const float* Mr = M + j*32;
    float q0=0.f,q1=0.f,q2=0.f,q3=0.f;
    #pragma unroll
    for (int k = 0; k < 32; k += 4){
      q0 += Mr[k]*e0[k];     q1 += Mr[k+1]*e0[k+1];
      q2 += Mr[k+2]*e0[k+2]; q3 += Mr[k+3]*e0[k+3];
    }
    hbuf[j*64 + lane] = tanh_fast(bM[j] + (q0+q1) + (q2+q3));
  }
  float h1[32];
  #pragma unroll
  for (int k = 0; k < 32; k++) h1[k] = hbuf[k*64 + lane];

  // ---- h2 = tanh(M c1 + bM + Whh h1), decode accumulated in-loop (no h2 round trip)
  float dv0 = decb[0], dv1 = decb[1], dv2 = decb[2], dv3 = decb[3], dv4 = decb[4];
  #pragma unroll 1
  for (int j = 0; j < 32; j++){
    const float* Mr = M + j*32;
    const float* Wr = whh + j*32;
    float q0=0.f,q1=0.f,q2=0.f,q3=0.f;
    #pragma unroll
    for (int k = 0; k < 32; k += 2){
      q0 += Mr[k]*dl[k];   q1 += Mr[k+1]*dl[k+1];
      q2 += Wr[k]*h1[k];   q3 += Wr[k+1]*h1[k+1];
    }
    float h2j = tanh_fast(bM[j] + (q0+q1) + (q2+q3));
    dv0 += decw[j]       * h2j;
    dv1 += decw[32 + j]  * h2j;
    dv2 += decw[64 + j]  * h2j;
    dv3 += decw[96 + j]  * h2j;
    dv4 += decw[128 + j] * h2j;
  }

  // ---- decode gelu + final linear
  float d0 = gelu_erf(dv0), d1 = gelu_erf(dv1), d2 = gelu_erf(dv2),
        d3 = gelu_erf(dv3), d4 = gelu_erf(dv4);
  float* yp = y + b*3ll;
  #pragma unroll
  for (int r = 0; r < 3; r++){
    yp[r] = outb[r] + outw[r*5+0]*d0 + outw[r*5+1]*d1
                    + outw[r*5+2]*d2 + outw[r*5+3]*d3 + outw[r*5+4]*d4;
  }
}

extern "C" void kernel_launch(void* const* d_in, const int* in_sizes, int n_in,
                              void* d_out, int out_size, void* d_ws, size_t ws_size,
                              hipStream_t stream){
  const float* x    = (const float*)d_in[0];
  const float* embw = (const float*)d_in[1];
  const float* embb = (const float*)d_in[2];
  const float* inw  = (const float*)d_in[3];
  const float* inb  = (const float*)d_in[4];
  const float* opw  = (const float*)d_in[5];
  const float* opb  = (const float*)d_in[6];
  const float* wih  = (const float*)d_in[7];
  const float* bih  = (const float*)d_in[8];
  const float* whh  = (const float*)d_in[9];
  const float* bhh  = (const float*)d_in[10];
  const float* decw = (const float*)d_in[11];
  const float* decb = (const float*)d_in[12];
  const float* outw = (const float*)d_in[13];
  const float* outb = (const float*)d_in[14];
  float* y  = (float*)d_out;
  float* ws = (float*)d_ws;   // needs 2112 floats (8.4 KB)

  int B = in_sizes[0] / 10;   // [B,2,5]

  prep_kernel<<<1, 1024, 0, stream>>>(inw, inb, opw, opb, wih, bih, bhh, ws);
  fused_kernel<<<(B + BT - 1)/BT, BT, 0, stream>>>(x, embw, embb, ws, whh,
                                                   decw, decb, outw, outb, y, B);
}

// Round 4
// 245.534 us; speedup vs baseline: 1.8969x; 1.3255x over previous
//
#include <hip/hip_runtime.h>
#include <math.h>

#define BT 128   // 2 waves of 64

typedef _Float16 half2v __attribute__((ext_vector_type(2)));
typedef __fp16   fp16x2 __attribute__((ext_vector_type(2)));

__device__ __forceinline__ half2v u2h(unsigned int u){
  union { unsigned int u; half2v h; } c; c.u = u; return c.h;
}
__device__ __forceinline__ unsigned int h2u(half2v h){
  union { unsigned int u; half2v h; } c; c.h = h; return c.u;
}
// v_cvt_pkrtz_f16_f32 returns __fp16x2; bit-cast to our _Float16x2 (same bits)
__device__ __forceinline__ half2v pkrtz(float a, float b){
  union { fp16x2 f; half2v h; } c;
  c.f = __builtin_amdgcn_cvt_pkrtz(a, b);
  return c.h;
}
__device__ __forceinline__ float fdot2(half2v a, half2v b, float c){
  return __builtin_amdgcn_fdot2(a, b, c, false);   // v_dot2_f32_f16
}
__device__ __forceinline__ float frcp(float x){ return __builtin_amdgcn_rcpf(x); }

// RNE f32x2 -> packed f16 (prep-side, off critical path)
__device__ __forceinline__ unsigned int pk_rne(float a, float b){
  half2v h; h.x = (_Float16)a; h.y = (_Float16)b; return h2u(h);
}

// gelu via A&S 7.1.25 erf (|eps|<=2.5e-5), v_rcp + v_exp
__device__ __forceinline__ float gelu_erf(float v){
  float z  = v * 0.70710678118654752f;
  float az = fabsf(z);
  float t  = frcp(fmaf(0.47047f, az, 1.0f));
  float poly = t*fmaf(t, fmaf(t, 0.7478556f, -0.0958798f), 0.3480242f);
  float ex = __expf(-az*az);
  float erfv = fmaf(-poly, ex, 1.0f);
  erfv = (z < 0.0f) ? -erfv : erfv;
  return 0.5f*v*(1.0f + erfv);
}

__device__ __forceinline__ float tanh_fast(float v){
  float t = __expf(2.0f*v);
  return 1.0f - 2.0f*frcp(t + 1.0f);   // stable: +inf->1, 0->-1
}

// ---------- prep: fold + pack weights (1 block, once per launch) ----------
// ws layout in u32 words:
//  [0,512)     A_pk   row d: 16 f16-pairs        A = Wq^T Wk
//  [512,544)   wvec   f32                        wvec = Wk^T bq
//  [544,1056)  M_pk   row j: 16 pairs            M = W_ih * OP * WV
//  [1056,1088) bM     f32                        bM = W_ih*(OP bv + opb) + b_ih + b_hh
//  [1088,1600) W_pk   whh rows packed
//  [1600,1680) dec_pk 5 rows x 16 pairs
//  [1680,1744) emb_pk row j: pairs (w0,w1),(w2,w3)
__global__ void prep_kernel(const float* __restrict__ inw, const float* __restrict__ inb,
                            const float* __restrict__ opw, const float* __restrict__ opb,
                            const float* __restrict__ wih, const float* __restrict__ bih,
                            const float* __restrict__ bhh, const float* __restrict__ whh,
                            const float* __restrict__ decw, const float* __restrict__ embw,
                            unsigned int* __restrict__ wsu){
  __shared__ float sA[1024], sP[1024], sM[1024], sT[32];
  float* wsf = (float*)wsu;
  int tx = threadIdx.x & 31;
  int ty = threadIdx.x >> 5;
  float accA = 0.f, accP = 0.f;
  #pragma unroll
  for (int m = 0; m < 32; m++){
    accA += inw[m*32 + ty] * inw[1024 + m*32 + tx];   // Wq[m,ty]*Wk[m,tx]
    accP += opw[ty*32 + m] * inw[2048 + m*32 + tx];   // OP[ty,m]*WV[m,tx]
  }
  sA[ty*32 + tx] = accA;
  sP[ty*32 + tx] = accP;
  if (ty == 0){
    float aw = 0.f;
    #pragma unroll
    for (int m = 0; m < 32; m++) aw += inb[m] * inw[1024 + m*32 + tx];
    wsf[512 + tx] = aw;
  }
  if (ty == 1){
    float at = opb[tx];
    #pragma unroll
    for (int m = 0; m < 32; m++) at += opw[tx*32 + m] * inb[64 + m];
    sT[tx] = at;
  }
  __syncthreads();
  float accM = 0.f;
  #pragma unroll
  for (int m = 0; m < 32; m++) accM += wih[ty*32 + m] * sP[m*32 + tx];
  sM[ty*32 + tx] = accM;
  if (ty == 2){
    float ab = bih[tx] + bhh[tx];
    #pragma unroll
    for (int m = 0; m < 32; m++) ab += wih[tx*32 + m] * sT[m];
    wsf[1056 + tx] = ab;
  }
  __syncthreads();
  int t = threadIdx.x;
  if (t < 512){
    int r = t >> 4, c = (t & 15)*2;
    wsu[t]        = pk_rne(sA[r*32+c],  sA[r*32+c+1]);
    wsu[544 + t]  = pk_rne(sM[r*32+c],  sM[r*32+c+1]);
    wsu[1088 + t] = pk_rne(whh[r*32+c], whh[r*32+c+1]);
  } else if (t < 592){
    int q = t - 512, i = q >> 4, c = (q & 15)*2;
    wsu[1600 + q] = pk_rne(decw[i*32+c], decw[i*32+c+1]);
  } else if (t < 656){
    int q = t - 592, j = q >> 1, c = (q & 1)*2;
    wsu[1680 + q] = pk_rne(embw[j*5+c], embw[j*5+c+1]);
  }
}

// ---------- main fused kernel: one thread per batch element ----------
__global__ __launch_bounds__(BT) void fused_kernel(
    const float* __restrict__ x,
    const unsigned int* __restrict__ wsu,
    const float* __restrict__ embw, const float* __restrict__ embb,
    const float* __restrict__ decb,
    const float* __restrict__ outw, const float* __restrict__ outb,
    float* __restrict__ y, int B)
{
  // per-wave slab: 32 rows x 64 lanes x u32 = 8 KB/wave (16 KB/block).
  // rows hold packed f16 (e0, delta); aliased by packed f16 (h1 even,odd) later.
  // wave lockstep -> no barriers needed; [row][lane] is bank-conflict-free.
  __shared__ unsigned int smem[(BT/64)*32*64];
  const float* wsf = (const float*)wsu;
  int tid = threadIdx.x, lane = tid & 63;
  unsigned int* slab = smem + (tid >> 6)*(32*64) + lane;

  long long b = (long long)blockIdx.x*BT + tid;
  if (b >= B) return;

  // x[b]: 10 floats, 8B-aligned
  const float2* xp = (const float2*)(x + b*10ll);
  float2 p0 = xp[0], p1 = xp[1], p2 = xp[2], p3 = xp[3], p4 = xp[4];
  half2v xa0 = pkrtz(p0.x, p0.y);
  half2v xb0 = pkrtz(p1.x, p1.y);
  float  x04 = p2.x;
  half2v xa1 = pkrtz(p2.y, p3.x);
  half2v xb1 = pkrtz(p3.y, p4.x);
  float  x14 = p4.y;

  // ---- embedding + gelu -> LDS as packed f16 (e0, delta)
  #pragma unroll 1
  for (int j = 0; j < 32; j++){
    unsigned int wp0 = wsu[1680 + j*2], wp1 = wsu[1680 + j*2 + 1];
    float w4 = embw[j*5 + 4], bb = embb[j];
    float a0 = fdot2(u2h(wp0), xa0, fdot2(u2h(wp1), xb0, fmaf(w4, x04, bb)));
    float a1 = fdot2(u2h(wp0), xa1, fdot2(u2h(wp1), xb1, fmaf(w4, x14, bb)));
    float g0 = gelu_erf(a0);
    float g1 = gelu_erf(a1);
    slab[j*64] = h2u(pkrtz(g0, g1 - g0));
  }

  // ---- rebuild register pairs: e0p[k]=(e0[2k],e0[2k+1]), dlp[k]=(dl[2k],dl[2k+1])
  half2v e0p[16], dlp[16];
  #pragma unroll
  for (int k = 0; k < 16; k++){
    unsigned int a = slab[(2*k)*64], c = slab[(2*k + 1)*64];
    e0p[k] = u2h((a & 0xffffu) | (c << 16));
    dlp[k] = u2h((a >> 16) | (c & 0xffff0000u));
  }

  // ---- score (delta identity): g_d = A_d . dl ; t0 = e0.g, t1 = dl.g, dw = wvec.dl
  float t0 = 0.f, t1 = 0.f, dw = 0.f;
  #pragma unroll 1
  for (int d = 0; d < 32; d++){
    const unsigned int* Ar = wsu + d*16;
    float g = 0.f;
    #pragma unroll
    for (int k = 0; k < 16; k++) g = fdot2(u2h(Ar[k]), dlp[k], g);
    half2v ev = u2h(slab[d*64]);       // runtime-indexed (e0[d], dl[d])
    float e0d = (float)ev.x, dld = (float)ev.y;
    t0 = fmaf(e0d, g, t0);
    t1 = fmaf(dld, g, t1);
    dw = fmaf(wsf[512 + d], dld, dw);
  }

  // ---- 2-way softmax on logit differences
  const float iss = 0.17677669529663689f;   // 1/sqrt(32)
  float a01 = frcp(1.0f + __expf(-((t0      + dw)*iss)));
  float a11 = frcp(1.0f + __expf(-((t0 + t1 + dw)*iss)));

  // ---- c_i = e0 + a_i1*delta, packed f16 (v_pk_fma_f16)
  _Float16 q01 = (_Float16)a01, q11 = (_Float16)a11;
  half2v s01 = {q01, q01}, s11 = {q11, q11};
  half2v c0p[16], c1p[16];
  #pragma unroll
  for (int k = 0; k < 16; k++){
    c0p[k] = dlp[k]*s01 + e0p[k];
    c1p[k] = dlp[k]*s11 + e0p[k];
  }

  // ---- h1 = tanh(M c0 + bM), two rows per iter, packed into LDS (aliases dead e-slab)
  #pragma unroll 1
  for (int j = 0; j < 16; j++){
    const unsigned int* M0 = wsu + 544 + (2*j)*16;
    float s0 = wsf[1056 + 2*j], s1 = wsf[1056 + 2*j + 1];
    #pragma unroll
    for (int k = 0; k < 16; k++){
      s0 = fdot2(u2h(M0[k]),      c0p[k], s0);
      s1 = fdot2(u2h(M0[16 + k]), c0p[k], s1);
    }
    slab[j*64] = h2u(pkrtz(tanh_fast(s0), tanh_fast(s1)));
  }
  half2v h1p[16];
  #pragma unroll
  for (int k = 0; k < 16; k++) h1p[k] = u2h(slab[k*64]);

  // ---- h2 = tanh(M c1 + Whh h1 + bM); decode accumulated in-loop via dot2
  float dv0 = decb[0], dv1 = decb[1], dv2 = decb[2], dv3 = decb[3], dv4 = decb[4];
  #pragma unroll 1
  for (int j = 0; j < 16; j++){
    const unsigned int* M0 = wsu + 544  + (2*j)*16;
    const unsigned int* W0 = wsu + 1088 + (2*j)*16;
    float s0 = wsf[1056 + 2*j], s1 = wsf[1056 + 2*j + 1];
    #pragma unroll
    for (int k = 0; k < 16; k++){
      s0 = fdot2(u2h(M0[k]),      c1p[k], s0);
      s0 = fdot2(u2h(W0[k]),      h1p[k], s0);
      s1 = fdot2(u2h(M0[16 + k]), c1p[k], s1);
      s1 = fdot2(u2h(W0[16 + k]), h1p[k], s1);
    }
    half2v h2p = pkrtz(tanh_fast(s0), tanh_fast(s1));
    dv0 = fdot2(u2h(wsu[1600 + j]),      h2p, dv0);
    dv1 = fdot2(u2h(wsu[1600 + 16 + j]), h2p, dv1);
    dv2 = fdot2(u2h(wsu[1600 + 32 + j]), h2p, dv2);
    dv3 = fdot2(u2h(wsu[1600 + 48 + j]), h2p, dv3);
    dv4 = fdot2(u2h(wsu[1600 + 64 + j]), h2p, dv4);
  }

  // ---- decode gelu + final linear
  float d0 = gelu_erf(dv0), d1 = gelu_erf(dv1), d2 = gelu_erf(dv2),
        d3 = gelu_erf(dv3), d4 = gelu_erf(dv4);
  float* yp = y + b*3ll;
  #pragma unroll
  for (int r = 0; r < 3; r++){
    yp[r] = outb[r] + outw[r*5+0]*d0 + outw[r*5+1]*d1
                    + outw[r*5+2]*d2 + outw[r*5+3]*d3 + outw[r*5+4]*d4;
  }
}

extern "C" void kernel_launch(void* const* d_in, const int* in_sizes, int n_in,
                              void* d_out, int out_size, void* d_ws, size_t ws_size,
                              hipStream_t stream){
  const float* x    = (const float*)d_in[0];
  const float* embw = (const float*)d_in[1];
  const float* embb = (const float*)d_in[2];
  const float* inw  = (const float*)d_in[3];
  const float* inb  = (const float*)d_in[4];
  const float* opw  = (const float*)d_in[5];
  const float* opb  = (const float*)d_in[6];
  const float* wih  = (const float*)d_in[7];
  const float* bih  = (const float*)d_in[8];
  const float* whh  = (const float*)d_in[9];
  const float* bhh  = (const float*)d_in[10];
  const float* decw = (const float*)d_in[11];
  const float* decb = (const float*)d_in[12];
  const float* outw = (const float*)d_in[13];
  const float* outb = (const float*)d_in[14];
  float* y = (float*)d_out;
  unsigned int* wsu = (unsigned int*)d_ws;   // needs 1744 u32 (7 KB)

  int B = in_sizes[0] / 10;   // [B,2,5]

  prep_kernel<<<1, 1024, 0, stream>>>(inw, inb, opw, opb, wih, bih, bhh,
                                      whh, decw, embw, wsu);
  fused_kernel<<<(B + BT - 1)/BT, BT, 0, stream>>>(x, wsu, embw, embb,
                                                   decb, outw, outb, y, B);
}

// Round 5
// 168.000 us; speedup vs baseline: 2.7723x; 1.4615x over previous
//
#include <hip/hip_runtime.h>
#include <math.h>

#define BT 256   // 4 waves; each wave = 32 batch elements

typedef _Float16 half2v __attribute__((ext_vector_type(2)));
typedef __fp16   fp16x2 __attribute__((ext_vector_type(2)));
typedef _Float16 half8  __attribute__((ext_vector_type(8)));
typedef float    f32x16 __attribute__((ext_vector_type(16)));

union U4H8 { unsigned int u[4]; half8 h; };

__device__ __forceinline__ half2v u2h(unsigned int u){
  union { unsigned int u; half2v h; } c; c.u = u; return c.h;
}
__device__ __forceinline__ unsigned int h2u(half2v h){
  union { unsigned int u; half2v h; } c; c.h = h; return c.u;
}
__device__ __forceinline__ half2v pkrtz(float a, float b){
  union { fp16x2 f; half2v h; } c;
  c.f = __builtin_amdgcn_cvt_pkrtz(a, b);
  return c.h;
}
__device__ __forceinline__ float fdot2(half2v a, half2v b, float c){
  return __builtin_amdgcn_fdot2(a, b, c, false);
}
__device__ __forceinline__ float frcp(float x){ return __builtin_amdgcn_rcpf(x); }

__device__ __forceinline__ unsigned int pk_rne(float a, float b){
  half2v h; h.x = (_Float16)a; h.y = (_Float16)b; return h2u(h);
}

// gelu via A&S 7.1.25 erf (|eps|<=2.5e-5)
__device__ __forceinline__ float gelu_erf(float v){
  float z  = v * 0.70710678118654752f;
  float az = fabsf(z);
  float t  = frcp(fmaf(0.47047f, az, 1.0f));
  float poly = t*fmaf(t, fmaf(t, 0.7478556f, -0.0958798f), 0.3480242f);
  float ex = __expf(-az*az);
  float erfv = fmaf(-poly, ex, 1.0f);
  erfv = (z < 0.0f) ? -erfv : erfv;
  return 0.5f*v*(1.0f + erfv);
}
__device__ __forceinline__ float tanh_fast(float v){
  float t = __expf(2.0f*v);
  return 1.0f - 2.0f*frcp(t + 1.0f);
}

// ---------------- ws layout (u32 words) ----------------
//  [0,512)     A_pk   : A = Wq^T Wk, row-major [32][32] f16 pairs
//  [512,1024)  M_pk   : M = W_ih*OP*WV
//  [1024,1536) W_pk   : whh
//  [1536,2048) dec_pk : rows 0-4 = decw, rows 5-31 = 0  ([32][32])
//  [2048,2304) emb_pk : [32 rows][16 f16] k<5 = embw, else 0
//  [2304,2320) wv_pk  : wvec = Wk^T bq, 32 f16
//  [2320,2352) bM_f   : f32, bM = W_ih*(OP bv + opb) + b_ih + b_hh
//  [2352,2384) decb_f : f32, rows 0-4 = decb, 5-31 = 0
__global__ void prep_kernel(const float* __restrict__ inw, const float* __restrict__ inb,
                            const float* __restrict__ opw, const float* __restrict__ opb,
                            const float* __restrict__ wih, const float* __restrict__ bih,
                            const float* __restrict__ bhh, const float* __restrict__ whh,
                            const float* __restrict__ decw, const float* __restrict__ embw,
                            const float* __restrict__ decb,
                            unsigned int* __restrict__ wsu){
  __shared__ float sA[1024], sP[1024], sM[1024], sT[32], sWV[32], sBM[32];
  int tx = threadIdx.x & 31;
  int ty = threadIdx.x >> 5;
  float accA = 0.f, accP = 0.f;
  #pragma unroll
  for (int m = 0; m < 32; m++){
    accA += inw[m*32 + ty] * inw[1024 + m*32 + tx];   // Wq[m,ty]*Wk[m,tx]
    accP += opw[ty*32 + m] * inw[2048 + m*32 + tx];   // OP[ty,m]*WV[m,tx]
  }
  sA[ty*32 + tx] = accA;
  sP[ty*32 + tx] = accP;
  if (ty == 0){
    float aw = 0.f;
    #pragma unroll
    for (int m = 0; m < 32; m++) aw += inb[m] * inw[1024 + m*32 + tx];
    sWV[tx] = aw;
  }
  if (ty == 1){
    float at = opb[tx];
    #pragma unroll
    for (int m = 0; m < 32; m++) at += opw[tx*32 + m] * inb[64 + m];
    sT[tx] = at;
  }
  __syncthreads();
  float accM = 0.f;
  #pragma unroll
  for (int m = 0; m < 32; m++) accM += wih[ty*32 + m] * sP[m*32 + tx];
  sM[ty*32 + tx] = accM;
  if (ty == 2){
    float ab = bih[tx] + bhh[tx];
    #pragma unroll
    for (int m = 0; m < 32; m++) ab += wih[tx*32 + m] * sT[m];
    sBM[tx] = ab;
  }
  __syncthreads();
  int t = threadIdx.x;
  if (t < 512){
    int r = t >> 4, c2 = (t & 15)*2;
    wsu[t]        = pk_rne(sA[r*32+c2],  sA[r*32+c2+1]);
    wsu[512 + t]  = pk_rne(sM[r*32+c2],  sM[r*32+c2+1]);
    wsu[1024 + t] = pk_rne(whh[r*32+c2], whh[r*32+c2+1]);
    wsu[1536 + t] = (r < 5) ? pk_rne(decw[r*32+c2], decw[r*32+c2+1]) : 0u;
  } else {
    int q = t - 512;
    if (q < 256){                         // emb_pk: [32][16] f16
      int j = q >> 3, cc = (q & 7)*2;
      float a = (cc   < 5) ? embw[j*5+cc]   : 0.f;
      float b = (cc+1 < 5) ? embw[j*5+cc+1] : 0.f;
      wsu[2048 + q] = pk_rne(a, b);
    } else if (q < 272){
      int k = (q - 256)*2;
      wsu[2304 + (q-256)] = pk_rne(sWV[k], sWV[k+1]);
    } else if (q < 304){
      ((float*)wsu)[2320 + (q-272)] = sBM[q-272];
    } else if (q < 336){
      int i = q - 304;
      ((float*)wsu)[2352 + i] = (i < 5) ? decb[i] : 0.f;
    }
  }
}

__device__ __forceinline__ half8 ldfrag(const unsigned int* __restrict__ p){
  U4H8 t; t.u[0]=p[0]; t.u[1]=p[1]; t.u[2]=p[2]; t.u[3]=p[3]; return t.h;
}

// C/D frag (16 f32, rows (i&3)+8*(i>>2)+4*grp) -> B-operand frags for K=32.
// Partner lane (lane^32) holds the complementary rows of the same column.
struct BF { U4H8 b1, b2; };
__device__ __forceinline__ BF toB(const float* v, bool g){
  unsigned int pk0=h2u(pkrtz(v[0], v[1])),  pk1=h2u(pkrtz(v[2], v[3]));
  unsigned int pk2=h2u(pkrtz(v[4], v[5])),  pk3=h2u(pkrtz(v[6], v[7]));
  unsigned int pk4=h2u(pkrtz(v[8], v[9])),  pk5=h2u(pkrtz(v[10],v[11]));
  unsigned int pk6=h2u(pkrtz(v[12],v[13])), pk7=h2u(pkrtz(v[14],v[15]));
  unsigned int s0 = g?pk0:pk2, s1 = g?pk1:pk3, s2 = g?pk4:pk6, s3 = g?pk5:pk7;
  unsigned int r0 = __shfl_xor(s0,32), r1 = __shfl_xor(s1,32);
  unsigned int r2 = __shfl_xor(s2,32), r3 = __shfl_xor(s3,32);
  BF o;
  o.b1.u[0]=g?r0:pk0; o.b1.u[1]=g?r1:pk1; o.b1.u[2]=g?pk2:r0; o.b1.u[3]=g?pk3:r1;
  o.b2.u[0]=g?r2:pk4; o.b2.u[1]=g?r3:pk5; o.b2.u[2]=g?pk6:r2; o.b2.u[3]=g?pk7:r3;
  return o;
}

__global__ __launch_bounds__(BT) void fused_kernel(
    const float* __restrict__ x,
    const unsigned int* __restrict__ wsu,
    const float* __restrict__ embb,
    const float* __restrict__ outw, const float* __restrict__ outb,
    float* __restrict__ y, int B)
{
  int tid  = threadIdx.x;
  int lane = tid & 63;
  int col  = lane & 31;
  bool g   = (lane >> 5) != 0;
  int grp  = g ? 1 : 0;
  long long base = ((long long)blockIdx.x*(BT/64) + (tid>>6)) * 32;
  if (base >= B) return;
  long long elem = base + col;

  // ---- constant fragments (A-operand: A[m=lane&31][k=8*grp+j]) ----
  const unsigned int* pA = wsu;
  const unsigned int* pM = wsu + 512;
  const unsigned int* pW = wsu + 1024;
  const unsigned int* pD = wsu + 1536;
  const unsigned int* pE = wsu + 2048;
  const unsigned int* pwv = wsu + 2304;
  const float* bMf = (const float*)(wsu + 2320);
  const float* dbf = (const float*)(wsu + 2352);

  half8 embA = ldfrag(pE + col*8  + grp*4);
  half8 A1   = ldfrag(pA + col*16 + grp*4), A2 = ldfrag(pA + col*16 + 8 + grp*4);
  half8 M1   = ldfrag(pM + col*16 + grp*4), M2 = ldfrag(pM + col*16 + 8 + grp*4);
  half8 W1   = ldfrag(pW + col*16 + grp*4), W2 = ldfrag(pW + col*16 + 8 + grp*4);
  half8 D1   = ldfrag(pD + col*16 + grp*4), D2 = ldfrag(pD + col*16 + 8 + grp*4);
  half2v wv1[4], wv2[4];
  #pragma unroll
  for (int j = 0; j < 4; j++){ wv1[j] = u2h(pwv[4*grp+j]); wv2[j] = u2h(pwv[8+4*grp+j]); }

  f32x16 cb_emb, cb_bM, cb_db;
  #pragma unroll
  for (int i = 0; i < 16; i++){
    int r = (i&3) + 8*(i>>2) + 4*grp;
    cb_emb[i] = embb[r]; cb_bM[i] = bMf[r]; cb_db[i] = dbf[r];
  }

  // ---- x load + B-frags (K=16: k0-4 = x, rest 0; group1 all 0) ----
  const float2* xp = (const float2*)(x + elem*10ll);
  float2 p0 = xp[0], p1 = xp[1], p2 = xp[2], p3 = xp[3], p4 = xp[4];
  U4H8 xb0, xb1;
  xb0.u[0] = g ? 0u : h2u(pkrtz(p0.x, p0.y));
  xb0.u[1] = g ? 0u : h2u(pkrtz(p1.x, p1.y));
  xb0.u[2] = g ? 0u : h2u(pkrtz(p2.x, 0.f));
  xb0.u[3] = 0u;
  xb1.u[0] = g ? 0u : h2u(pkrtz(p2.y, p3.x));
  xb1.u[1] = g ? 0u : h2u(pkrtz(p3.y, p4.x));
  xb1.u[2] = g ? 0u : h2u(pkrtz(p4.y, 0.f));
  xb1.u[3] = 0u;

  // ---- embedding (bias via C) + gelu ----
  f32x16 e0D = __builtin_amdgcn_mfma_f32_32x32x16_f16(embA, xb0.h, cb_emb, 0,0,0);
  f32x16 e1D = __builtin_amdgcn_mfma_f32_32x32x16_f16(embA, xb1.h, cb_emb, 0,0,0);
  float e0[16], dl[16];
  #pragma unroll
  for (int i = 0; i < 16; i++){
    float a = gelu_erf(e0D[i]);
    float b = gelu_erf(e1D[i]);
    e0[i] = a; dl[i] = b - a;
  }

  // ---- score: g = A*delta (MFMA), then per-column dots ----
  BF e0B = toB(e0, g);
  BF dB  = toB(dl, g);
  f32x16 z16;
  #pragma unroll
  for (int i = 0; i < 16; i++) z16[i] = 0.f;
  f32x16 gD = __builtin_amdgcn_mfma_f32_32x32x16_f16(A1, dB.b1.h, z16, 0,0,0);
  gD = __builtin_amdgcn_mfma_f32_32x32x16_f16(A2, dB.b2.h, gD, 0,0,0);

  float t0 = 0.f, t1 = 0.f, dw = 0.f;
  #pragma unroll
  for (int i = 0; i < 16; i++){ t0 = fmaf(e0[i], gD[i], t0); t1 = fmaf(dl[i], gD[i], t1); }
  #pragma unroll
  for (int j = 0; j < 4; j++){
    dw = fdot2(wv1[j], u2h(dB.b1.u[j]), dw);
    dw = fdot2(wv2[j], u2h(dB.b2.u[j]), dw);
  }
  t0 += __shfl_xor(t0, 32);
  t1 += __shfl_xor(t1, 32);
  dw += __shfl_xor(dw, 32);

  const float iss = 0.17677669529663689f;   // 1/sqrt(32)
  float a01 = frcp(1.0f + __expf(-((t0      + dw)*iss)));
  float a11 = frcp(1.0f + __expf(-((t0 + t1 + dw)*iss)));

  // ---- c_i = e0 + a_i1*delta directly in B-space (pk_fma_f16) ----
  _Float16 q01 = (_Float16)a01, q11 = (_Float16)a11;
  half8 v01 = {q01,q01,q01,q01,q01,q01,q01,q01};
  half8 v11 = {q11,q11,q11,q11,q11,q11,q11,q11};
  half8 c0B1 = dB.b1.h*v01 + e0B.b1.h, c0B2 = dB.b2.h*v01 + e0B.b2.h;
  half8 c1B1 = dB.b1.h*v11 + e0B.b1.h, c1B2 = dB.b2.h*v11 + e0B.b2.h;

  // ---- h1 = tanh(M c0 + bM) ----
  f32x16 h1D = __builtin_amdgcn_mfma_f32_32x32x16_f16(M1, c0B1, cb_bM, 0,0,0);
  h1D = __builtin_amdgcn_mfma_f32_32x32x16_f16(M2, c0B2, h1D, 0,0,0);
  float h1f[16];
  #pragma unroll
  for (int i = 0; i < 16; i++) h1f[i] = tanh_fast(h1D[i]);
  BF h1B = toB(h1f, g);

  // ---- h2 = tanh(M c1 + Whh h1 + bM) ----
  f32x16 h2D = __builtin_amdgcn_mfma_f32_32x32x16_f16(M1, c1B1, cb_bM, 0,0,0);
  h2D = __builtin_amdgcn_mfma_f32_32x32x16_f16(M2, c1B2, h2D, 0,0,0);
  h2D = __builtin_amdgcn_mfma_f32_32x32x16_f16(W1, h1B.b1.h, h2D, 0,0,0);
  h2D = __builtin_amdgcn_mfma_f32_32x32x16_f16(W2, h1B.b2.h, h2D, 0,0,0);
  float h2f[16];
  #pragma unroll
  for (int i = 0; i < 16; i++) h2f[i] = tanh_fast(h2D[i]);
  BF h2B = toB(h2f, g);

  // ---- decode: dv rows 0-4 (dec padded to 32 rows), bias via C ----
  f32x16 dvD = __builtin_amdgcn_mfma_f32_32x32x16_f16(D1, h2B.b1.h, cb_db, 0,0,0);
  dvD = __builtin_amdgcn_mfma_f32_32x32x16_f16(D2, h2B.b2.h, dvD, 0,0,0);
  // grp0 regs 0-3 = dv0..3 ; grp1 reg 0 = dv4
  float dv4 = __shfl_xor(dvD[0], 32);

  float d0 = gelu_erf(dvD[0]), d1 = gelu_erf(dvD[1]), d2 = gelu_erf(dvD[2]),
        d3 = gelu_erf(dvD[3]), d4 = gelu_erf(dv4);
  float y0 = outb[0] + outw[0]*d0 + outw[1]*d1 + outw[2]*d2 + outw[3]*d3 + outw[4]*d4;
  float y1 = outb[1] + outw[5]*d0 + outw[6]*d1 + outw[7]*d2 + outw[8]*d3 + outw[9]*d4;
  float y2 = outb[2] + outw[10]*d0 + outw[11]*d1 + outw[12]*d2 + outw[13]*d3 + outw[14]*d4;
  if (lane < 32){
    float* yp = y + elem*3ll;
    yp[0] = y0; yp[1] = y1; yp[2] = y2;
  }
}

extern "C" void kernel_launch(void* const* d_in, const int* in_sizes, int n_in,
                              void* d_out, int out_size, void* d_ws, size_t ws_size,
                              hipStream_t stream){
  const float* x    = (const float*)d_in[0];
  const float* embw = (const float*)d_in[1];
  const float* embb = (const float*)d_in[2];
  const float* inw  = (const float*)d_in[3];
  const float* inb  = (const float*)d_in[4];
  const float* opw  = (const float*)d_in[5];
  const float* opb  = (const float*)d_in[6];
  const float* wih  = (const float*)d_in[7];
  const float* bih  = (const float*)d_in[8];
  const float* whh  = (const float*)d_in[9];
  const float* bhh  = (const float*)d_in[10];
  const float* decw = (const float*)d_in[11];
  const float* decb = (const float*)d_in[12];
  const float* outw = (const float*)d_in[13];
  const float* outb = (const float*)d_in[14];
  float* y = (float*)d_out;
  unsigned int* wsu = (unsigned int*)d_ws;   // 2384 u32 = 9.6 KB

  int B = in_sizes[0] / 10;                  // [B,2,5]
  int elems_per_block = (BT/64)*32;          // 128

  prep_kernel<<<1, 1024, 0, stream>>>(inw, inb, opw, opb, wih, bih, bhh,
                                      whh, decw, embw, decb, wsu);
  fused_kernel<<<(B + elems_per_block - 1)/elems_per_block, BT, 0, stream>>>(
      x, wsu, embb, outw, outb, y, B);
}

// Round 6
// 155.551 us; speedup vs baseline: 2.9941x; 1.0800x over previous
//
#include <hip/hip_runtime.h>
#include <math.h>

#define BT 256   // 4 waves; each wave = 32 batch elements

typedef _Float16 half2v __attribute__((ext_vector_type(2)));
typedef __fp16   fp16x2 __attribute__((ext_vector_type(2)));
typedef _Float16 half8  __attribute__((ext_vector_type(8)));
typedef float    f32x16 __attribute__((ext_vector_type(16)));

union U4H8 { unsigned int u[4]; half8 h; };

__device__ __forceinline__ half2v u2h(unsigned int u){
  union { unsigned int u; half2v h; } c; c.u = u; return c.h;
}
__device__ __forceinline__ unsigned int h2u(half2v h){
  union { unsigned int u; half2v h; } c; c.h = h; return c.u;
}
__device__ __forceinline__ half2v pkrtz(float a, float b){
  union { fp16x2 f; half2v h; } c;
  c.f = __builtin_amdgcn_cvt_pkrtz(a, b);
  return c.h;
}
__device__ __forceinline__ float fdot2(half2v a, half2v b, float c){
  return __builtin_amdgcn_fdot2(a, b, c, false);
}
__device__ __forceinline__ float frcp(float x){ return __builtin_amdgcn_rcpf(x); }

__device__ __forceinline__ unsigned int pk_rne(float a, float b){
  half2v h; h.x = (_Float16)a; h.y = (_Float16)b; return h2u(h);
}

// f32 exp-based gelu (decode only, 5/lane) — A&S 7.1.25 erf, |eps|<=2.5e-5
__device__ __forceinline__ float gelu_erf(float v){
  float z  = v * 0.70710678118654752f;
  float az = fabsf(z);
  float t  = frcp(fmaf(0.47047f, az, 1.0f));
  float poly = t*fmaf(t, fmaf(t, 0.7478556f, -0.0958798f), 0.3480242f);
  float ex = __expf(-az*az);
  float erfv = fmaf(-poly, ex, 1.0f);
  erfv = (z < 0.0f) ? -erfv : erfv;
  return 0.5f*v*(1.0f + erfv);
}
__device__ __forceinline__ float tanh_fast(float v){
  float t = __expf(2.0f*v);
  return 1.0f - 2.0f*frcp(t + 1.0f);
}

// packed-f16 gelu: gelu(x) = x*S, S = clamp(0.5 + x*q(x^2), 0, 1).
// q = Newton fit of (Phi(sqrt(t))-0.5)/sqrt(t) at t=0..4 (uniform nodes);
// checked midpoints: |gelu err| <= 2.3e-4 on |x|<=2 (inputs bounded ~1.7 at 6 sigma).
__device__ __forceinline__ half2v gelu_pk(half2v x){
  const _Float16 a0 = (_Float16)0.3989423f,  a1 = (_Float16)-0.0663157f,
                 a2 = (_Float16)0.0096298f,  a3 = (_Float16)-0.00095967f,
                 a4 = (_Float16)0.000048f,   hp = (_Float16)0.5f,
                 hn = (_Float16)-0.5f;
  const half2v A0={a0,a0}, A1={a1,a1}, A2={a2,a2}, A3={a3,a3}, A4={a4,a4};
  const half2v HP={hp,hp}, HN={hn,hn};
  half2v t = x*x;
  half2v q = A4*t + A3;
  q = q*t + A2;
  q = q*t + A1;
  q = q*t + A0;
  half2v u = x*q;
#if __has_builtin(__builtin_elementwise_min)
  u = __builtin_elementwise_max(u, HN);
  u = __builtin_elementwise_min(u, HP);
#else
  u.x = u.x > hp ? hp : (u.x < hn ? hn : u.x);
  u.y = u.y > hp ? hp : (u.y < hn ? hn : u.y);
#endif
  return x*(u + HP);
}

// ---------------- ws layout (u32 words) ----------------
//  [0,512)     A_pk   : A = Wq^T Wk, row-major [32][32] f16 pairs
//  [512,1024)  M_pk   : M = W_ih*OP*WV
//  [1024,1536) W_pk   : whh
//  [1536,2048) dec_pk : rows 0-4 = decw, rows 5-31 = 0  ([32][32])
//  [2048,2304) emb_pk : [32 rows][16 f16] k<5 = embw, else 0
//  [2304,2320) wv_pk  : wvec = Wk^T bq, 32 f16
//  [2320,2352) bM_f   : f32, bM = W_ih*(OP bv + opb) + b_ih + b_hh
//  [2352,2384) decb_f : f32, rows 0-4 = decb, 5-31 = 0
__global__ void prep_kernel(const float* __restrict__ inw, const float* __restrict__ inb,
                            const float* __restrict__ opw, const float* __restrict__ opb,
                            const float* __restrict__ wih, const float* __restrict__ bih,
                            const float* __restrict__ bhh, const float* __restrict__ whh,
                            const float* __restrict__ decw, const float* __restrict__ embw,
                            const float* __restrict__ decb,
                            unsigned int* __restrict__ wsu){
  __shared__ float sA[1024], sP[1024], sM[1024], sT[32], sWV[32], sBM[32];
  int tx = threadIdx.x & 31;
  int ty = threadIdx.x >> 5;
  float accA = 0.f, accP = 0.f;
  #pragma unroll
  for (int m = 0; m < 32; m++){
    accA += inw[m*32 + ty] * inw[1024 + m*32 + tx];   // Wq[m,ty]*Wk[m,tx]
    accP += opw[ty*32 + m] * inw[2048 + m*32 + tx];   // OP[ty,m]*WV[m,tx]
  }
  sA[ty*32 + tx] = accA;
  sP[ty*32 + tx] = accP;
  if (ty == 0){
    float aw = 0.f;
    #pragma unroll
    for (int m = 0; m < 32; m++) aw += inb[m] * inw[1024 + m*32 + tx];
    sWV[tx] = aw;
  }
  if (ty == 1){
    float at = opb[tx];
    #pragma unroll
    for (int m = 0; m < 32; m++) at += opw[tx*32 + m] * inb[64 + m];
    sT[tx] = at;
  }
  __syncthreads();
  float accM = 0.f;
  #pragma unroll
  for (int m = 0; m < 32; m++) accM += wih[ty*32 + m] * sP[m*32 + tx];
  sM[ty*32 + tx] = accM;
  if (ty == 2){
    float ab = bih[tx] + bhh[tx];
    #pragma unroll
    for (int m = 0; m < 32; m++) ab += wih[tx*32 + m] * sT[m];
    sBM[tx] = ab;
  }
  __syncthreads();
  int t = threadIdx.x;
  if (t < 512){
    int r = t >> 4, c2 = (t & 15)*2;
    wsu[t]        = pk_rne(sA[r*32+c2],  sA[r*32+c2+1]);
    wsu[512 + t]  = pk_rne(sM[r*32+c2],  sM[r*32+c2+1]);
    wsu[1024 + t] = pk_rne(whh[r*32+c2], whh[r*32+c2+1]);
    wsu[1536 + t] = (r < 5) ? pk_rne(decw[r*32+c2], decw[r*32+c2+1]) : 0u;
  } else {
    int q = t - 512;
    if (q < 256){                         // emb_pk: [32][16] f16
      int j = q >> 3, cc = (q & 7)*2;
      float a = (cc   < 5) ? embw[j*5+cc]   : 0.f;
      float b = (cc+1 < 5) ? embw[j*5+cc+1] : 0.f;
      wsu[2048 + q] = pk_rne(a, b);
    } else if (q < 272){
      int k = (q - 256)*2;
      wsu[2304 + (q-256)] = pk_rne(sWV[k], sWV[k+1]);
    } else if (q < 304){
      ((float*)wsu)[2320 + (q-272)] = sBM[q-272];
    } else if (q < 336){
      int i = q - 304;
      ((float*)wsu)[2352 + i] = (i < 5) ? decb[i] : 0.f;
    }
  }
}

__device__ __forceinline__ half8 ldfrag(const unsigned int* __restrict__ p){
  U4H8 t; t.u[0]=p[0]; t.u[1]=p[1]; t.u[2]=p[2]; t.u[3]=p[3]; return t.h;
}

// packed C-layout pairs (pk[i] = rows (2i,2i+1) of this lane's half) -> B-frags.
// Partner lane (lane^32) holds the complementary rows of the same column.
struct BF { U4H8 b1, b2; };
__device__ __forceinline__ BF toB_pk(const unsigned int* pk, bool g){
  unsigned int s0 = g?pk[0]:pk[2], s1 = g?pk[1]:pk[3],
               s2 = g?pk[4]:pk[6], s3 = g?pk[5]:pk[7];
  unsigned int r0 = __shfl_xor(s0,32), r1 = __shfl_xor(s1,32);
  unsigned int r2 = __shfl_xor(s2,32), r3 = __shfl_xor(s3,32);
  BF o;
  o.b1.u[0]=g?r0:pk[0]; o.b1.u[1]=g?r1:pk[1]; o.b1.u[2]=g?pk[2]:r0; o.b1.u[3]=g?pk[3]:r1;
  o.b2.u[0]=g?r2:pk[4]; o.b2.u[1]=g?r3:pk[5]; o.b2.u[2]=g?pk[6]:r2; o.b2.u[3]=g?pk[7]:r3;
  return o;
}

// load 16 bias values (f32) for this lane's C-frag rows via 4x float4
__device__ __forceinline__ f32x16 ldbias(const float* __restrict__ p, int grp){
  const float4* b = (const float4*)(p + 4*grp);
  float4 q0 = b[0], q1 = b[2], q2 = b[4], q3 = b[6];
  f32x16 c;
  c[0]=q0.x; c[1]=q0.y; c[2]=q0.z; c[3]=q0.w;
  c[4]=q1.x; c[5]=q1.y; c[6]=q1.z; c[7]=q1.w;
  c[8]=q2.x; c[9]=q2.y; c[10]=q2.z; c[11]=q2.w;
  c[12]=q3.x; c[13]=q3.y; c[14]=q3.z; c[15]=q3.w;
  return c;
}

__global__ __launch_bounds__(BT) void fused_kernel(
    const float* __restrict__ x,
    const unsigned int* __restrict__ wsu,
    const float* __restrict__ embb,
    const float* __restrict__ outw, const float* __restrict__ outb,
    float* __restrict__ y, int B)
{
  int tid  = threadIdx.x;
  int lane = tid & 63;
  int col  = lane & 31;
  bool g   = (lane >> 5) != 0;
  int grp  = g ? 1 : 0;
  long long base = ((long long)blockIdx.x*(BT/64) + (tid>>6)) * 32;
  if (base >= B) return;
  long long elem = base + col;

  // ---- constant fragments (A-operand: A[m=lane&31][k=8*grp+j]) ----
  const unsigned int* pA = wsu;
  const unsigned int* pM = wsu + 512;
  const unsigned int* pW = wsu + 1024;
  const unsigned int* pD = wsu + 1536;
  const unsigned int* pE = wsu + 2048;
  const unsigned int* pwv = wsu + 2304;
  const float* bMf = (const float*)(wsu + 2320);
  const float* dbf = (const float*)(wsu + 2352);

  half8 embA = ldfrag(pE + col*8  + grp*4);
  half8 A1   = ldfrag(pA + col*16 + grp*4), A2 = ldfrag(pA + col*16 + 8 + grp*4);
  half8 M1   = ldfrag(pM + col*16 + grp*4), M2 = ldfrag(pM + col*16 + 8 + grp*4);
  half8 W1   = ldfrag(pW + col*16 + grp*4), W2 = ldfrag(pW + col*16 + 8 + grp*4);
  half8 D1   = ldfrag(pD + col*16 + grp*4), D2 = ldfrag(pD + col*16 + 8 + grp*4);
  half2v wv1[4], wv2[4];
  #pragma unroll
  for (int j = 0; j < 4; j++){ wv1[j] = u2h(pwv[4*grp+j]); wv2[j] = u2h(pwv[8+4*grp+j]); }

  f32x16 cb_emb = ldbias(embb, grp);
  f32x16 cb_bM  = ldbias(bMf,  grp);
  f32x16 cb_db  = ldbias(dbf,  grp);

  // ---- x load + B-frags (K=16: k0-4 = x, rest 0; group1 all 0) ----
  const float2* xp = (const float2*)(x + elem*10ll);
  float2 p0 = xp[0], p1 = xp[1], p2 = xp[2], p3 = xp[3], p4 = xp[4];
  U4H8 xb0, xb1;
  xb0.u[0] = g ? 0u : h2u(pkrtz(p0.x, p0.y));
  xb0.u[1] = g ? 0u : h2u(pkrtz(p1.x, p1.y));
  xb0.u[2] = g ? 0u : h2u(pkrtz(p2.x, 0.f));
  xb0.u[3] = 0u;
  xb1.u[0] = g ? 0u : h2u(pkrtz(p2.y, p3.x));
  xb1.u[1] = g ? 0u : h2u(pkrtz(p3.y, p4.x));
  xb1.u[2] = g ? 0u : h2u(pkrtz(p4.y, 0.f));
  xb1.u[3] = 0u;

  // ---- embedding (bias via C) + packed-f16 gelu ----
  f32x16 e0D = __builtin_amdgcn_mfma_f32_32x32x16_f16(embA, xb0.h, cb_emb, 0,0,0);
  f32x16 e1D = __builtin_amdgcn_mfma_f32_32x32x16_f16(embA, xb1.h, cb_emb, 0,0,0);
  unsigned int epk[8], dlpk[8];
  #pragma unroll
  for (int i = 0; i < 8; i++){
    half2v e0h = gelu_pk(pkrtz(e0D[2*i], e0D[2*i+1]));
    half2v e1h = gelu_pk(pkrtz(e1D[2*i], e1D[2*i+1]));
    epk[i]  = h2u(e0h);
    dlpk[i] = h2u(e1h - e0h);
  }

  // ---- score: g = A*delta (MFMA), dots via v_dot2 on packed pairs ----
  BF e0B = toB_pk(epk, g);
  BF dB  = toB_pk(dlpk, g);
  f32x16 z16;
  #pragma unroll
  for (int i = 0; i < 16; i++) z16[i] = 0.f;
  f32x16 gD = __builtin_amdgcn_mfma_f32_32x32x16_f16(A1, dB.b1.h, z16, 0,0,0);
  gD = __builtin_amdgcn_mfma_f32_32x32x16_f16(A2, dB.b2.h, gD, 0,0,0);

  float t0 = 0.f, t1 = 0.f, dw = 0.f;
  #pragma unroll
  for (int i = 0; i < 8; i++){
    half2v gp = pkrtz(gD[2*i], gD[2*i+1]);
    t0 = fdot2(u2h(epk[i]),  gp, t0);
    t1 = fdot2(u2h(dlpk[i]), gp, t1);
  }
  #pragma unroll
  for (int j = 0; j < 4; j++){
    dw = fdot2(wv1[j], u2h(dB.b1.u[j]), dw);
    dw = fdot2(wv2[j], u2h(dB.b2.u[j]), dw);
  }
  t0 += __shfl_xor(t0, 32);
  t1 += __shfl_xor(t1, 32);
  dw += __shfl_xor(dw, 32);

  const float iss = 0.17677669529663689f;   // 1/sqrt(32)
  float a01 = frcp(1.0f + __expf(-((t0      + dw)*iss)));
  float a11 = frcp(1.0f + __expf(-((t0 + t1 + dw)*iss)));

  // ---- c0 = e0 + a01*delta; c1 = c0 + (a11-a01)*delta, in B-space ----
  _Float16 q01 = (_Float16)a01, qda = (_Float16)(a11 - a01);
  half8 v01 = {q01,q01,q01,q01,q01,q01,q01,q01};
  half8 vda = {qda,qda,qda,qda,qda,qda,qda,qda};
  half8 c0B1 = dB.b1.h*v01 + e0B.b1.h, c0B2 = dB.b2.h*v01 + e0B.b2.h;
  half8 c1B1 = dB.b1.h*vda + c0B1,     c1B2 = dB.b2.h*vda + c0B2;

  // ---- h1 = tanh(M c0 + bM) ----
  f32x16 h1D = __builtin_amdgcn_mfma_f32_32x32x16_f16(M1, c0B1, cb_bM, 0,0,0);
  h1D = __builtin_amdgcn_mfma_f32_32x32x16_f16(M2, c0B2, h1D, 0,0,0);
  unsigned int h1pk[8];
  #pragma unroll
  for (int i = 0; i < 8; i++)
    h1pk[i] = h2u(pkrtz(tanh_fast(h1D[2*i]), tanh_fast(h1D[2*i+1])));
  BF h1B = toB_pk(h1pk, g);

  // ---- h2 = tanh(M c1 + Whh h1 + bM) ----
  f32x16 h2D = __builtin_amdgcn_mfma_f32_32x32x16_f16(M1, c1B1, cb_bM, 0,0,0);
  h2D = __builtin_amdgcn_mfma_f32_32x32x16_f16(M2, c1B2, h2D, 0,0,0);
  h2D = __builtin_amdgcn_mfma_f32_32x32x16_f16(W1, h1B.b1.h, h2D, 0,0,0);
  h2D = __builtin_amdgcn_mfma_f32_32x32x16_f16(W2, h1B.b2.h, h2D, 0,0,0);
  unsigned int h2pk[8];
  #pragma unroll
  for (int i = 0; i < 8; i++)
    h2pk[i] = h2u(pkrtz(tanh_fast(h2D[2*i]), tanh_fast(h2D[2*i+1])));
  BF h2B = toB_pk(h2pk, g);

  // ---- decode: dv rows 0-4 (dec padded to 32 rows), bias via C ----
  f32x16 dvD = __builtin_amdgcn_mfma_f32_32x32x16_f16(D1, h2B.b1.h, cb_db, 0,0,0);
  dvD = __builtin_amdgcn_mfma_f32_32x32x16_f16(D2, h2B.b2.h, dvD, 0,0,0);
  // grp0 regs 0-3 = dv0..3 ; grp1 reg 0 = dv4
  float dv4 = __shfl_xor(dvD[0], 32);

  float d0 = gelu_erf(dvD[0]), d1 = gelu_erf(dvD[1]), d2 = gelu_erf(dvD[2]),
        d3 = gelu_erf(dvD[3]), d4 = gelu_erf(dv4);
  float y0 = outb[0] + outw[0]*d0 + outw[1]*d1 + outw[2]*d2 + outw[3]*d3 + outw[4]*d4;
  float y1 = outb[1] + outw[5]*d0 + outw[6]*d1 + outw[7]*d2 + outw[8]*d3 + outw[9]*d4;
  float y2 = outb[2] + outw[10]*d0 + outw[11]*d1 + outw[12]*d2 + outw[13]*d3 + outw[14]*d4;
  if (lane < 32){
    float* yp = y + elem*3ll;
    yp[0] = y0; yp[1] = y1; yp[2] = y2;
  }
}

extern "C" void kernel_launch(void* const* d_in, const int* in_sizes, int n_in,
                              void* d_out, int out_size, void* d_ws, size_t ws_size,
                              hipStream_t stream){
  const float* x    = (const float*)d_in[0];
  const float* embw = (const float*)d_in[1];
  const float* embb = (const float*)d_in[2];
  const float* inw  = (const float*)d_in[3];
  const float* inb  = (const float*)d_in[4];
  const float* opw  = (const float*)d_in[5];
  const float* opb  = (const float*)d_in[6];
  const float* wih  = (const float*)d_in[7];
  const float* bih  = (const float*)d_in[8];
  const float* whh  = (const float*)d_in[9];
  const float* bhh  = (const float*)d_in[10];
  const float* decw = (const float*)d_in[11];
  const float* decb = (const float*)d_in[12];
  const float* outw = (const float*)d_in[13];
  const float* outb = (const float*)d_in[14];
  float* y = (float*)d_out;
  unsigned int* wsu = (unsigned int*)d_ws;   // 2384 u32 = 9.6 KB

  int B = in_sizes[0] / 10;                  // [B,2,5]
  int elems_per_block = (BT/64)*32;          // 128

  prep_kernel<<<1, 1024, 0, stream>>>(inw, inb, opw, opb, wih, bih, bhh,
                                      whh, decw, embw, decb, wsu);
  fused_kernel<<<(B + elems_per_block - 1)/elems_per_block, BT, 0, stream>>>(
      x, wsu, embb, outw, outb, y, B);
}